// Round 7
// baseline (363.471 us; speedup 1.0000x reference)
//
#include <hip/hip_runtime.h>

// ---------------------------------------------------------------------------
// Attention: out = softmax(BETA * (X_q Wq + bq)(X_k Wk + bk)^T) (X_v Wv + bv)
// B=4, S=2048, D=1024, KEY_DIM=VALUE_DIM=1024, BETA=1/32.
// R13 = R11 (best, 337us) + cast3 eliminated via reg-staged fp32 A:
//  - proj loads X fp32 as float4 -> regs (coalesced), cvt to bf16 in-reg
//    (RNE, bit-identical to cast3), ds_write_b128 into R11's EXACT bf16
//    LDS layout (proven 0 bank conflicts). B stays global_load_lds.
//  - R12's failure modes avoided: dbuf kept (1 syncthreads/K-tile), no new
//    LDS layout (R12's fp32-in-LDS swizzle had 4.2M conflicts + single-buf).
//  - A(t+1) loads issued before tile-t MFMA -> HBM latency hidden (T14);
//    compiler auto-waits vmcnt before the cvt (normal loads).
//  - scores/pv/softmax/transpose verbatim R11.
// ---------------------------------------------------------------------------

typedef __bf16 bf16x8 __attribute__((ext_vector_type(8)));
typedef float f32x4 __attribute__((ext_vector_type(4)));

#define MIB ((size_t)1 << 20)

__device__ __forceinline__ unsigned short f2b(float f) {
  unsigned int u = __float_as_uint(f);
  return (unsigned short)((u + 0x7FFFu + ((u >> 16) & 1u)) >> 16);
}

__device__ __forceinline__ void async16(const void* g, void* l) {
  __builtin_amdgcn_global_load_lds(
      (const __attribute__((address_space(1))) unsigned int*)g,
      (__attribute__((address_space(3))) unsigned int*)l, 16, 0, 0);
}

__device__ __forceinline__ unsigned ldsoff(const void* p) {
  return (unsigned)(size_t)(const __attribute__((address_space(3))) char*)p;
}

// Raw b128 LDS read, invisible to the compiler's waitcnt insertion.
__device__ __forceinline__ bf16x8 ds_read16(unsigned off) {
  bf16x8 r;
  asm volatile("ds_read_b128 %0, %1" : "=v"(r) : "v"(off));
  return r;
}

// ---------------------------------------------------------------------------
// Projection GEMM K-loop: fp32 A reg-staged (cvt->bf16->ds_write), bf16 B via
// global_load_lds. LDS: 2 buffers x (A 16KB + B 16KB) = 64KB, R11 layout:
// chunk slot (r,cc) holds global chunk (r, cc^(r&7)), 64 bf16 per row.
// 4 waves 2x2; wave tile 64x64. SWAP=true -> transposed C fragment.
// ---------------------------------------------------------------------------
template <bool SWAP>
__device__ __forceinline__ void gemm_loop_projf(
    const float* __restrict__ A, const unsigned short* __restrict__ Bt,
    unsigned short* lds, int K, int m0, int n0, f32x4 (&acc)[4][4]) {
  const int tid = threadIdx.x;
  const int lane = tid & 63;
  const int wave = tid >> 6;
  const int wm = (wave >> 1) * 64;
  const int wn = (wave & 1) * 64;
  const int fr = lane & 15;
  const int q = lane >> 4;
  const int NT = K >> 6;

  const float* Ab = A + (size_t)m0 * K;
  const unsigned short* Bb = Bt + (size_t)n0 * K;
  const unsigned LB = ldsoff(lds);

  // Loop-invariant fragment byte offsets (within a 32KB buffer) — R11 exact.
  unsigned oa[4][2], ob[4][2];
#pragma unroll
  for (int mi = 0; mi < 4; ++mi) {
    const int R = wm + mi * 16 + fr;
#pragma unroll
    for (int ks = 0; ks < 2; ++ks) {
      const int kc = ks * 4 + q;
      oa[mi][ks] = (unsigned)((R * 64 + ((kc ^ (R & 7)) << 3)) * 2);
    }
  }
#pragma unroll
  for (int ni = 0; ni < 4; ++ni) {
    const int R = wn + ni * 16 + fr;
#pragma unroll
    for (int ks = 0; ks < 2; ++ks) {
      const int kc = ks * 4 + q;
      ob[ni][ks] = (unsigned)(16384 + (R * 64 + ((kc ^ (R & 7)) << 3)) * 2);
    }
  }

  // Staging helpers. Thread covers chunks e = i*256+tid, i=0..3 (8 bf16 each).
  float4 ar[4][2];
  auto issueA = [&](int kb) {
#pragma unroll
    for (int i = 0; i < 4; ++i) {
      const int e = i * 256 + tid;
      const int r = e >> 3;
      const int cg = (e & 7) ^ (r & 7);
      const float* src = Ab + (size_t)r * K + kb + cg * 8;
      ar[i][0] = *(const float4*)src;
      ar[i][1] = *(const float4*)(src + 4);
    }
  };
  auto issueB = [&](int kb, int buf) {
#pragma unroll
    for (int i = 0; i < 4; ++i) {
      const int e = i * 256 + tid;
      const int r = e >> 3;
      const int cg = (e & 7) ^ (r & 7);
      async16(Bb + (size_t)r * K + kb + cg * 8, lds + buf * 16384 + 8192 + e * 8);
    }
  };
  auto writeA = [&](int buf) {
#pragma unroll
    for (int i = 0; i < 4; ++i) {
      const int e = i * 256 + tid;
      bf16x8 w;
      w[0] = (__bf16)ar[i][0].x; w[1] = (__bf16)ar[i][0].y;
      w[2] = (__bf16)ar[i][0].z; w[3] = (__bf16)ar[i][0].w;
      w[4] = (__bf16)ar[i][1].x; w[5] = (__bf16)ar[i][1].y;
      w[6] = (__bf16)ar[i][1].z; w[7] = (__bf16)ar[i][1].w;
      *(bf16x8*)&lds[buf * 16384 + e * 8] = w;
    }
  };

  // Prologue: tile 0 -> buffer 0.
  issueA(0);
  issueB(0, 0);
  writeA(0);        // compiler inserts the vmcnt wait for ar
  __syncthreads();  // drains ds_writes + B asyncs; tile 0 resident

  for (int t = 0; t < NT; ++t) {
    const int cur = t & 1;
    const unsigned boff = LB + (unsigned)cur * 32768;
    if (t + 1 < NT) {
      issueA((t + 1) << 6);     // HBM latency hides under MFMA below
      issueB((t + 1) << 6, cur ^ 1);
    }

    bf16x8 av[2][4], bv[2][4];
#pragma unroll
    for (int ks = 0; ks < 2; ++ks)
#pragma unroll
      for (int mi = 0; mi < 4; ++mi) av[ks][mi] = ds_read16(boff + oa[mi][ks]);
#pragma unroll
    for (int ks = 0; ks < 2; ++ks)
#pragma unroll
      for (int ni = 0; ni < 4; ++ni) bv[ks][ni] = ds_read16(boff + ob[ni][ks]);

    asm volatile("s_waitcnt lgkmcnt(0)");
    __builtin_amdgcn_sched_barrier(0);

#pragma unroll
    for (int ks = 0; ks < 2; ++ks)
#pragma unroll
      for (int mi = 0; mi < 4; ++mi)
#pragma unroll
        for (int ni = 0; ni < 4; ++ni)
          acc[mi][ni] = SWAP ? __builtin_amdgcn_mfma_f32_16x16x32_bf16(
                                   bv[ks][ni], av[ks][mi], acc[mi][ni], 0, 0, 0)
                             : __builtin_amdgcn_mfma_f32_16x16x32_bf16(
                                   av[ks][mi], bv[ks][ni], acc[mi][ni], 0, 0, 0);

    if (t + 1 < NT) writeA(cur ^ 1);  // into the buffer freed at last barrier
    __syncthreads();  // drains writes + B asyncs: tile t+1 resident
  }
}

// ---------------------------------------------------------------------------
// bf16-input GEMM K-loop (scores / PV), double-buffered — verbatim R11.
// ---------------------------------------------------------------------------
template <int TN>
__device__ __forceinline__ void stage_tile(
    const unsigned short* __restrict__ A, const unsigned short* __restrict__ Bt,
    unsigned short* dst, int K, int kb, int tid) {
#pragma unroll
  for (int i = 0; i < 4; ++i) {
    const int e = i * 256 + tid;
    const int r = e >> 3;
    const int cg = (e & 7) ^ (r & 7);
    async16(A + (size_t)r * K + kb + cg * 8, dst + e * 8);
  }
#pragma unroll
  for (int i = 0; i < TN / 32; ++i) {
    const int e = i * 256 + tid;
    const int r = e >> 3;
    const int cg = (e & 7) ^ (r & 7);
    async16(Bt + (size_t)r * K + kb + cg * 8, dst + 128 * 64 + e * 8);
  }
}

template <int TN, bool SWAP>
__device__ __forceinline__ void gemm_loop(
    const unsigned short* __restrict__ A, const unsigned short* __restrict__ Bt,
    unsigned short* lds, int K, int m0, int n0, f32x4 (&acc)[4][TN / 32]) {
  constexpr int NI = TN / 32;
  constexpr unsigned BUFB = (128 + TN) * 64 * 2;  // bytes per buffer
  const int tid = threadIdx.x;
  const int lane = tid & 63;
  const int wave = tid >> 6;
  const int wm = (wave >> 1) * 64;
  const int wn = (wave & 1) * (TN / 2);
  const int fr = lane & 15;
  const int q = lane >> 4;
  const int NT = K >> 6;

  const unsigned short* Ab = A + (size_t)m0 * K;
  const unsigned short* Bb = Bt + (size_t)n0 * K;
  const unsigned LB = ldsoff(lds);

  unsigned oa[4][2], ob[NI][2];
#pragma unroll
  for (int mi = 0; mi < 4; ++mi) {
    const int R = wm + mi * 16 + fr;
#pragma unroll
    for (int ks = 0; ks < 2; ++ks) {
      const int kc = ks * 4 + q;
      oa[mi][ks] = (unsigned)((R * 64 + ((kc ^ (R & 7)) << 3)) * 2);
    }
  }
#pragma unroll
  for (int ni = 0; ni < NI; ++ni) {
    const int R = wn + ni * 16 + fr;
#pragma unroll
    for (int ks = 0; ks < 2; ++ks) {
      const int kc = ks * 4 + q;
      ob[ni][ks] =
          (unsigned)(128 * 64 * 2 + (R * 64 + ((kc ^ (R & 7)) << 3)) * 2);
    }
  }

  stage_tile<TN>(Ab, Bb, lds, K, 0, tid);
  __syncthreads();

  for (int t = 0; t < NT; ++t) {
    const unsigned boff = LB + (unsigned)(t & 1) * BUFB;
    if (t + 1 < NT)
      stage_tile<TN>(Ab, Bb, lds + ((t + 1) & 1) * (BUFB / 2), K,
                     (t + 1) << 6, tid);

    bf16x8 av[2][4], bv[2][NI];
#pragma unroll
    for (int ks = 0; ks < 2; ++ks)
#pragma unroll
      for (int mi = 0; mi < 4; ++mi) av[ks][mi] = ds_read16(boff + oa[mi][ks]);
#pragma unroll
    for (int ks = 0; ks < 2; ++ks)
#pragma unroll
      for (int ni = 0; ni < NI; ++ni) bv[ks][ni] = ds_read16(boff + ob[ni][ks]);

    asm volatile("s_waitcnt lgkmcnt(0)");
    __builtin_amdgcn_sched_barrier(0);

#pragma unroll
    for (int ks = 0; ks < 2; ++ks)
#pragma unroll
      for (int mi = 0; mi < 4; ++mi)
#pragma unroll
        for (int ni = 0; ni < NI; ++ni)
          acc[mi][ni] = SWAP ? __builtin_amdgcn_mfma_f32_16x16x32_bf16(
                                   bv[ks][ni], av[ks][mi], acc[mi][ni], 0, 0, 0)
                             : __builtin_amdgcn_mfma_f32_16x16x32_bf16(
                                   av[ks][mi], bv[ks][ni], acc[mi][ni], 0, 0, 0);

    __syncthreads();
  }
}

// ---------------------------------------------------------------------------
// q/k projection (SWAP layout, fp32 X input), grid (8, 64, 2): z = {q,k}.
// ---------------------------------------------------------------------------
struct ProjArgs {
  const float* A[3];
  const unsigned short* Bt[3];
  unsigned short* C[3];
  const float* bias[3];
};

__global__ __launch_bounds__(256) void proj_qk(ProjArgs p) {
  __shared__ __align__(16) unsigned short lds[2 * 16384];
  const int z = blockIdx.z;
  const int m0 = blockIdx.y * 128;
  const int n0 = blockIdx.x * 128;

  f32x4 acc[4][4] = {};
  gemm_loop_projf<true>(p.A[z], p.Bt[z], lds, 1024, m0, n0, acc);

  const int lane = threadIdx.x & 63;
  const int wave = threadIdx.x >> 6;
  const int wm = (wave >> 1) * 64;
  const int wn = (wave & 1) * 64;
  const int fr = lane & 15;
  const int q4 = (lane >> 4) * 4;
  const float* bias = p.bias[z];
  unsigned short* C = p.C[z];

  // SWAP layout: row m = fr (+16*mi), cols n = q4 + r (+16*ni).
#pragma unroll
  for (int mi = 0; mi < 4; ++mi) {
    const int m = m0 + wm + mi * 16 + fr;
#pragma unroll
    for (int ni = 0; ni < 4; ++ni) {
      const int nb = n0 + wn + ni * 16 + q4;
      const float4 bb = *(const float4*)&bias[nb];
      ushort4 o = make_ushort4(
          f2b(acc[mi][ni][0] + bb.x), f2b(acc[mi][ni][1] + bb.y),
          f2b(acc[mi][ni][2] + bb.z), f2b(acc[mi][ni][3] + bb.w));
      *(ushort4*)&C[(size_t)m * 1024 + nb] = o;
    }
  }
}

// ---------------------------------------------------------------------------
// v projection (unswapped, fp32 X input), grid (8, 64, 1): writes vT[b][n][s].
// ---------------------------------------------------------------------------
__global__ __launch_bounds__(256) void proj_v(ProjArgs p) {
  __shared__ __align__(16) unsigned short lds[2 * 16384];
  const int m0 = blockIdx.y * 128;
  const int n0 = blockIdx.x * 128;

  f32x4 acc[4][4] = {};
  gemm_loop_projf<false>(p.A[2], p.Bt[2], lds, 1024, m0, n0, acc);

  const int lane = threadIdx.x & 63;
  const int wave = threadIdx.x >> 6;
  const int wm = (wave >> 1) * 64;
  const int wn = (wave & 1) * 64;
  const int fr = lane & 15;
  const int q4 = (lane >> 4) * 4;
  const float* bias = p.bias[2];

  // vT: per-batch [1024, 2048]; col n = fr (+16*ni), rows m = q4+r (+16*mi).
  unsigned short* C = p.C[2] + (size_t)(m0 >> 11) * (2048 * 1024);
#pragma unroll
  for (int mi = 0; mi < 4; ++mi) {
#pragma unroll
    for (int ni = 0; ni < 4; ++ni) {
      const int col = n0 + wn + ni * 16 + fr;
      const float bb = bias[col];
      const int rowb = (m0 + wm + mi * 16 + q4) & 2047;
      ushort4 o =
          make_ushort4(f2b(acc[mi][ni][0] + bb), f2b(acc[mi][ni][1] + bb),
                       f2b(acc[mi][ni][2] + bb), f2b(acc[mi][ni][3] + bb));
      *(ushort4*)&C[(size_t)col * 2048 + rowb] = o;
    }
  }
}

// ---------------------------------------------------------------------------
// Batched GEMM, fp32 out (SWAP layout -> float4 stores) — verbatim R11.
// ---------------------------------------------------------------------------
__global__ __launch_bounds__(256) void gemm_f32(
    const unsigned short* __restrict__ A, const unsigned short* __restrict__ Bt,
    float* __restrict__ C, int K, int ldc, long long sA, long long sB,
    long long sC) {
  __shared__ __align__(16) unsigned short lds[2 * 256 * 64];
  const int bz = blockIdx.z;
  A += (long long)bz * sA;
  Bt += (long long)bz * sB;
  C += (long long)bz * sC;
  const int m0 = blockIdx.y * 128;
  const int n0 = blockIdx.x * 128;

  f32x4 acc[4][4] = {};
  gemm_loop<128, true>(A, Bt, lds, K, m0, n0, acc);

  const int lane = threadIdx.x & 63;
  const int wave = threadIdx.x >> 6;
  const int wm = (wave >> 1) * 64;
  const int wn = (wave & 1) * 64;
  const int fr = lane & 15;
  const int q4 = (lane >> 4) * 4;
#pragma unroll
  for (int mi = 0; mi < 4; ++mi) {
    const int m = m0 + wm + mi * 16 + fr;
#pragma unroll
    for (int ni = 0; ni < 4; ++ni) {
      const int nb = n0 + wn + ni * 16 + q4;
      *(f32x4*)&C[(size_t)m * ldc + nb] = acc[mi][ni];
    }
  }
}

// ---------------------------------------------------------------------------
// Merged cast + transpose W [K,N] fp32 -> WT [N,K] bf16; z selects weight.
// ---------------------------------------------------------------------------
__global__ __launch_bounds__(256) void transpose3(
    const float* __restrict__ w0, const float* __restrict__ w1,
    const float* __restrict__ w2, unsigned short* __restrict__ t0,
    unsigned short* __restrict__ t1, unsigned short* __restrict__ t2) {
  __shared__ float t[32][33];
  const int K = 1024, N = 1024;
  const float* W = (blockIdx.z == 0) ? w0 : (blockIdx.z == 1) ? w1 : w2;
  unsigned short* WT = (blockIdx.z == 0) ? t0 : (blockIdx.z == 1) ? t1 : t2;
  const int n0 = blockIdx.x * 32, k0 = blockIdx.y * 32;
  const int tx = threadIdx.x, ty = threadIdx.y;  // block (32,8)
#pragma unroll
  for (int i = 0; i < 32; i += 8)
    t[ty + i][tx] = W[(size_t)(k0 + ty + i) * N + (n0 + tx)];
  __syncthreads();
#pragma unroll
  for (int i = 0; i < 32; i += 8)
    WT[(size_t)(n0 + ty + i) * K + (k0 + tx)] = f2b(t[tx][ty + i]);
}

// ---------------------------------------------------------------------------
// Row softmax: P[row,:] = softmax(BETA * S[row,:]) as bf16. One block/row.
// ---------------------------------------------------------------------------
__global__ __launch_bounds__(256) void softmax_rows(const float* __restrict__ S,
                                                    unsigned short* __restrict__ P) {
  const int cols = 2048;
  const size_t row = blockIdx.x;
  const float4* srow = (const float4*)(S + row * cols);
  const int tid = threadIdx.x;
  const int lane = tid & 63;
  const int wave = tid >> 6;

  float4 a = srow[tid];
  float4 b = srow[tid + 256];

  float mx = fmaxf(fmaxf(fmaxf(a.x, a.y), fmaxf(a.z, a.w)),
                   fmaxf(fmaxf(b.x, b.y), fmaxf(b.z, b.w)));
#pragma unroll
  for (int o = 1; o < 64; o <<= 1) mx = fmaxf(mx, __shfl_xor(mx, o));

  __shared__ float red[8];
  if (lane == 0) red[wave] = mx;
  __syncthreads();
  mx = fmaxf(fmaxf(red[0], red[1]), fmaxf(red[2], red[3]));

  const float c = 0.03125f * 1.4426950408889634f;  // BETA * log2(e)
  float4 pa, pb;
  pa.x = exp2f((a.x - mx) * c); pa.y = exp2f((a.y - mx) * c);
  pa.z = exp2f((a.z - mx) * c); pa.w = exp2f((a.w - mx) * c);
  pb.x = exp2f((b.x - mx) * c); pb.y = exp2f((b.y - mx) * c);
  pb.z = exp2f((b.z - mx) * c); pb.w = exp2f((b.w - mx) * c);

  float sum = pa.x + pa.y + pa.z + pa.w + pb.x + pb.y + pb.z + pb.w;
#pragma unroll
  for (int o = 1; o < 64; o <<= 1) sum += __shfl_xor(sum, o);
  if (lane == 0) red[4 + wave] = sum;
  __syncthreads();
  sum = red[4] + red[5] + red[6] + red[7];

  const float inv = 1.0f / sum;
  ushort4* prow = (ushort4*)(P + row * cols);
  prow[tid] = make_ushort4(f2b(pa.x * inv), f2b(pa.y * inv), f2b(pa.z * inv),
                           f2b(pa.w * inv));
  prow[tid + 256] = make_ushort4(f2b(pb.x * inv), f2b(pb.y * inv),
                                 f2b(pb.z * inv), f2b(pb.w * inv));
}

// ---------------------------------------------------------------------------
extern "C" void kernel_launch(void* const* d_in, const int* in_sizes, int n_in,
                              void* d_out, int out_size, void* d_ws, size_t ws_size,
                              hipStream_t stream) {
  const float* query = (const float*)d_in[0];
  const float* key_ = (const float*)d_in[1];
  const float* value = (const float*)d_in[2];
  const float* Wq = (const float*)d_in[3];
  const float* bq = (const float*)d_in[4];
  const float* Wk = (const float*)d_in[5];
  const float* bk = (const float*)d_in[6];
  const float* Wv = (const float*)d_in[7];
  const float* bv = (const float*)d_in[8];
  float* out = (float*)d_out;

  char* ws = (char*)d_ws;
  // Workspace layout (peak 166 MiB):
  //   [0,6)      WqT/WkT/WvT bf16 [1024,1024]
  //   [6,54)     P bf16 [8192,2048]
  //   [54,102)   q bf16 [8192,1024], k bf16 [8192,1024], vT bf16 [4][1024,2048]
  //   [102,166)  scores fp32 [4,2048,2048]
  unsigned short* WqT = (unsigned short*)ws;
  unsigned short* WkT = WqT + (size_t)1024 * 1024;
  unsigned short* WvT = WkT + (size_t)1024 * 1024;
  unsigned short* qb = (unsigned short*)(ws + 54 * MIB);
  unsigned short* kb = (unsigned short*)(ws + 70 * MIB);
  unsigned short* vT = (unsigned short*)(ws + 86 * MIB);
  float* sc = (float*)(ws + 102 * MIB);
  unsigned short* P = (unsigned short*)(ws + 6 * MIB);

  transpose3<<<dim3(32, 32, 3), dim3(32, 8), 0, stream>>>(Wq, Wk, Wv, WqT, WkT,
                                                          WvT);

  ProjArgs pa;
  pa.A[0] = query;  pa.A[1] = key_;  pa.A[2] = value;
  pa.Bt[0] = WqT; pa.Bt[1] = WkT; pa.Bt[2] = WvT;
  pa.C[0] = qb;  pa.C[1] = kb;  pa.C[2] = vT;
  pa.bias[0] = bq; pa.bias[1] = bk; pa.bias[2] = bv;

  // q,k projections: swapped layout, ushort4 stores. 1024 blocks.
  proj_qk<<<dim3(8, 64, 2), 256, 0, stream>>>(pa);
  // v projection: unswapped, transposed vT out. 512 blocks.
  proj_v<<<dim3(8, 64, 1), 256, 0, stream>>>(pa);

  // scores[b] = q[b] @ k[b]^T : M=N=2048, K=1024, fp32 out. 1024 blocks.
  gemm_f32<<<dim3(16, 16, 4), 256, 0, stream>>>(
      qb, kb, sc, 1024, 2048, 2048LL * 1024, 2048LL * 1024, 2048LL * 2048);

  // P = softmax(BETA * scores), bf16
  softmax_rows<<<8192, 256, 0, stream>>>(sc, P);

  // out[b] = P[b] @ v[b] : M=2048, N=1024, K=2048. 512 blocks.
  gemm_f32<<<dim3(8, 16, 4), 256, 0, stream>>>(
      P, vT, out, 2048, 1024, 2048LL * 2048, 1024LL * 2048, 2048LL * 1024);
}

// Round 8
// 319.706 us; speedup vs baseline: 1.1369x; 1.1369x over previous
//
#include <hip/hip_runtime.h>

// ---------------------------------------------------------------------------
// Attention: out = softmax(BETA * (X_q Wq + bq)(X_k Wk + bk)^T) (X_v Wv + bv)
// B=4, S=2048, D=1024, KEY_DIM=VALUE_DIM=1024, BETA=1/32.
// R14 = R11 (best, 337us) + two zero-kernel-body-risk changes:
//  - GRID DECODE SWAP (m-tile fastest) on proj/scores/pv: blocks sharing an
//    A-panel are now gridDim.x (=64/16/16, all %8==0) apart -> same XCD under
//    round-robin -> panel fetched once per XCD instead of 8x. R13 taught that
//    A-side reuse traffic dominates FETCH (133MB vs 37MB ideal on proj).
//    Unlike R5's chunked swizzle, consecutive bids still round-robin XCDs
//    evenly (no dispatch imbalance).
//  - cast3+transpose3 merged into one `prep` dispatch (one fewer launch gap).
//  Everything else (gemm bodies, LDS swizzle, epilogues, softmax) = R11.
// ---------------------------------------------------------------------------

typedef __bf16 bf16x8 __attribute__((ext_vector_type(8)));
typedef float f32x4 __attribute__((ext_vector_type(4)));

#define MIB ((size_t)1 << 20)

__device__ __forceinline__ unsigned short f2b(float f) {
  unsigned int u = __float_as_uint(f);
  return (unsigned short)((u + 0x7FFFu + ((u >> 16) & 1u)) >> 16);
}

__device__ __forceinline__ void async16(const void* g, void* l) {
  __builtin_amdgcn_global_load_lds(
      (const __attribute__((address_space(1))) unsigned int*)g,
      (__attribute__((address_space(3))) unsigned int*)l, 16, 0, 0);
}

__device__ __forceinline__ unsigned ldsoff(const void* p) {
  return (unsigned)(size_t)(const __attribute__((address_space(3))) char*)p;
}

// Raw b128 LDS read, invisible to the compiler's waitcnt insertion.
__device__ __forceinline__ bf16x8 ds_read16(unsigned off) {
  bf16x8 r;
  asm volatile("ds_read_b128 %0, %1" : "=v"(r) : "v"(off));
  return r;
}

// ---------------------------------------------------------------------------
// Stage one K-tile (A:128x64 + B:TNx64 bf16) into LDS buffer `dst`.
// LDS slot (r,cc) holds global chunk (r, cc^(r&7)) (XOR swizzle, both-sides).
// ---------------------------------------------------------------------------
template <int TN>
__device__ __forceinline__ void stage_tile(
    const unsigned short* __restrict__ A, const unsigned short* __restrict__ Bt,
    unsigned short* dst, int K, int kb, int tid) {
#pragma unroll
  for (int i = 0; i < 4; ++i) {
    const int e = i * 256 + tid;
    const int r = e >> 3;
    const int cg = (e & 7) ^ (r & 7);
    async16(A + (size_t)r * K + kb + cg * 8, dst + e * 8);
  }
#pragma unroll
  for (int i = 0; i < TN / 32; ++i) {
    const int e = i * 256 + tid;
    const int r = e >> 3;
    const int cg = (e & 7) ^ (r & 7);
    async16(Bt + (size_t)r * K + kb + cg * 8, dst + 128 * 64 + e * 8);
  }
}

// ---------------------------------------------------------------------------
// 2-phase double-buffered GEMM K-loop: acc += A[128xK] * Bt[TNxK]^T, BK=64.
// 4 waves 2x2; wave tile 64 x (TN/2). SWAP=true computes the transposed
// C-fragment (lane owns 4 consecutive n) for vectorized epilogues.
// lds must hold 2*(128+TN)*64 ushorts.
// ---------------------------------------------------------------------------
template <int TN, bool SWAP>
__device__ __forceinline__ void gemm_loop(
    const unsigned short* __restrict__ A, const unsigned short* __restrict__ Bt,
    unsigned short* lds, int K, int m0, int n0, f32x4 (&acc)[4][TN / 32]) {
  constexpr int NI = TN / 32;
  constexpr unsigned BUFB = (128 + TN) * 64 * 2;  // bytes per buffer
  const int tid = threadIdx.x;
  const int lane = tid & 63;
  const int wave = tid >> 6;
  const int wm = (wave >> 1) * 64;
  const int wn = (wave & 1) * (TN / 2);
  const int fr = lane & 15;
  const int q = lane >> 4;
  const int NT = K >> 6;

  const unsigned short* Ab = A + (size_t)m0 * K;
  const unsigned short* Bb = Bt + (size_t)n0 * K;
  const unsigned LB = ldsoff(lds);

  unsigned oa[4][2], ob[NI][2];
#pragma unroll
  for (int mi = 0; mi < 4; ++mi) {
    const int R = wm + mi * 16 + fr;
#pragma unroll
    for (int ks = 0; ks < 2; ++ks) {
      const int kc = ks * 4 + q;
      oa[mi][ks] = (unsigned)((R * 64 + ((kc ^ (R & 7)) << 3)) * 2);
    }
  }
#pragma unroll
  for (int ni = 0; ni < NI; ++ni) {
    const int R = wn + ni * 16 + fr;
#pragma unroll
    for (int ks = 0; ks < 2; ++ks) {
      const int kc = ks * 4 + q;
      ob[ni][ks] =
          (unsigned)(128 * 64 * 2 + (R * 64 + ((kc ^ (R & 7)) << 3)) * 2);
    }
  }

  stage_tile<TN>(Ab, Bb, lds, K, 0, tid);
  __syncthreads();

  for (int t = 0; t < NT; ++t) {
    const unsigned boff = LB + (unsigned)(t & 1) * BUFB;
    if (t + 1 < NT)
      stage_tile<TN>(Ab, Bb, lds + ((t + 1) & 1) * (BUFB / 2), K,
                     (t + 1) << 6, tid);

    bf16x8 av[2][4], bv[2][NI];
#pragma unroll
    for (int ks = 0; ks < 2; ++ks)
#pragma unroll
      for (int mi = 0; mi < 4; ++mi) av[ks][mi] = ds_read16(boff + oa[mi][ks]);
#pragma unroll
    for (int ks = 0; ks < 2; ++ks)
#pragma unroll
      for (int ni = 0; ni < NI; ++ni) bv[ks][ni] = ds_read16(boff + ob[ni][ks]);

    asm volatile("s_waitcnt lgkmcnt(0)");
    __builtin_amdgcn_sched_barrier(0);

#pragma unroll
    for (int ks = 0; ks < 2; ++ks)
#pragma unroll
      for (int mi = 0; mi < 4; ++mi)
#pragma unroll
        for (int ni = 0; ni < NI; ++ni)
          acc[mi][ni] = SWAP ? __builtin_amdgcn_mfma_f32_16x16x32_bf16(
                                   bv[ks][ni], av[ks][mi], acc[mi][ni], 0, 0, 0)
                             : __builtin_amdgcn_mfma_f32_16x16x32_bf16(
                                   av[ks][mi], bv[ks][ni], acc[mi][ni], 0, 0, 0);

    __syncthreads();
  }
}

// ---------------------------------------------------------------------------
// q/k projection GEMM (SWAP layout), grid (64, 8, 2): x = m-tile (fastest ->
// A-panel mates are 64 apart -> same XCD), y = n-tile, z = {q,k}.
// ---------------------------------------------------------------------------
struct ProjArgs {
  const unsigned short* A[3];
  const unsigned short* Bt[3];
  unsigned short* C[3];
  const float* bias[3];
};

__global__ __launch_bounds__(256) void proj_qk(ProjArgs p) {
  __shared__ __align__(16) unsigned short lds[2 * 256 * 64];
  const int z = blockIdx.z;
  const int m0 = blockIdx.x * 128;  // m fastest
  const int n0 = blockIdx.y * 128;

  f32x4 acc[4][4] = {};
  gemm_loop<128, true>(p.A[z], p.Bt[z], lds, 1024, m0, n0, acc);

  const int lane = threadIdx.x & 63;
  const int wave = threadIdx.x >> 6;
  const int wm = (wave >> 1) * 64;
  const int wn = (wave & 1) * 64;
  const int fr = lane & 15;
  const int q4 = (lane >> 4) * 4;
  const float* bias = p.bias[z];
  unsigned short* C = p.C[z];

  // SWAP layout: row m = fr (+16*mi), cols n = q4 + r (+16*ni), 4 consecutive.
#pragma unroll
  for (int mi = 0; mi < 4; ++mi) {
    const int m = m0 + wm + mi * 16 + fr;
#pragma unroll
    for (int ni = 0; ni < 4; ++ni) {
      const int nb = n0 + wn + ni * 16 + q4;
      const float4 bb = *(const float4*)&bias[nb];
      ushort4 o = make_ushort4(
          f2b(acc[mi][ni][0] + bb.x), f2b(acc[mi][ni][1] + bb.y),
          f2b(acc[mi][ni][2] + bb.z), f2b(acc[mi][ni][3] + bb.w));
      *(ushort4*)&C[(size_t)m * 1024 + nb] = o;
    }
  }
}

// ---------------------------------------------------------------------------
// v projection GEMM (unswapped), grid (64, 8, 1): writes vT[b][n][s].
// ---------------------------------------------------------------------------
__global__ __launch_bounds__(256) void proj_v(ProjArgs p) {
  __shared__ __align__(16) unsigned short lds[2 * 256 * 64];
  const int m0 = blockIdx.x * 128;  // m fastest
  const int n0 = blockIdx.y * 128;

  f32x4 acc[4][4] = {};
  gemm_loop<128, false>(p.A[2], p.Bt[2], lds, 1024, m0, n0, acc);

  const int lane = threadIdx.x & 63;
  const int wave = threadIdx.x >> 6;
  const int wm = (wave >> 1) * 64;
  const int wn = (wave & 1) * 64;
  const int fr = lane & 15;
  const int q4 = (lane >> 4) * 4;
  const float* bias = p.bias[2];

  // vT: per-batch [1024, 2048]; col n = fr (+16*ni), rows m = q4+r (+16*mi).
  unsigned short* C = p.C[2] + (size_t)(m0 >> 11) * (2048 * 1024);
#pragma unroll
  for (int mi = 0; mi < 4; ++mi) {
#pragma unroll
    for (int ni = 0; ni < 4; ++ni) {
      const int col = n0 + wn + ni * 16 + fr;
      const float bb = bias[col];
      const int rowb = (m0 + wm + mi * 16 + q4) & 2047;
      ushort4 o =
          make_ushort4(f2b(acc[mi][ni][0] + bb), f2b(acc[mi][ni][1] + bb),
                       f2b(acc[mi][ni][2] + bb), f2b(acc[mi][ni][3] + bb));
      *(ushort4*)&C[(size_t)col * 2048 + rowb] = o;
    }
  }
}

// ---------------------------------------------------------------------------
// Batched GEMM, fp32 out (SWAP layout -> float4 stores), m-tile fastest:
// m0 = blockIdx.x, n0 = blockIdx.y. C[bz][m,n] = sum_k A[bz][m,k]*Bt[bz][n,k]
// ---------------------------------------------------------------------------
__global__ __launch_bounds__(256) void gemm_f32(
    const unsigned short* __restrict__ A, const unsigned short* __restrict__ Bt,
    float* __restrict__ C, int K, int ldc, long long sA, long long sB,
    long long sC) {
  __shared__ __align__(16) unsigned short lds[2 * 256 * 64];
  const int bz = blockIdx.z;
  A += (long long)bz * sA;
  Bt += (long long)bz * sB;
  C += (long long)bz * sC;
  const int m0 = blockIdx.x * 128;  // m fastest
  const int n0 = blockIdx.y * 128;

  f32x4 acc[4][4] = {};
  gemm_loop<128, true>(A, Bt, lds, K, m0, n0, acc);

  const int lane = threadIdx.x & 63;
  const int wave = threadIdx.x >> 6;
  const int wm = (wave >> 1) * 64;
  const int wn = (wave & 1) * 64;
  const int fr = lane & 15;
  const int q4 = (lane >> 4) * 4;
#pragma unroll
  for (int mi = 0; mi < 4; ++mi) {
    const int m = m0 + wm + mi * 16 + fr;
#pragma unroll
    for (int ni = 0; ni < 4; ++ni) {
      const int nb = n0 + wn + ni * 16 + q4;
      *(f32x4*)&C[(size_t)m * ldc + nb] = acc[mi][ni];
    }
  }
}

// ---------------------------------------------------------------------------
// prep: cast3 (fp32->bf16, 3 tensors) + transpose3 (W->WT bf16) in ONE
// dispatch. Blocks [0,24576): cast; [24576,27648): transpose. 256 threads.
// ---------------------------------------------------------------------------
__global__ __launch_bounds__(256) void prep(
    const float4* __restrict__ xq, const float4* __restrict__ xk,
    const float4* __restrict__ xv, ushort4* __restrict__ oq,
    ushort4* __restrict__ ok, ushort4* __restrict__ ov,
    const float* __restrict__ w0, const float* __restrict__ w1,
    const float* __restrict__ w2, unsigned short* __restrict__ t0,
    unsigned short* __restrict__ t1, unsigned short* __restrict__ t2) {
  __shared__ float tl[32][33];
  const int bid = blockIdx.x;
  if (bid < 24576) {
    const int ten = bid >> 13;  // 8192 blocks per tensor
    const int i = (bid & 8191) * 256 + threadIdx.x;
    const float4* src = (ten == 0) ? xq : (ten == 1) ? xk : xv;
    ushort4* dst = (ten == 0) ? oq : (ten == 1) ? ok : ov;
    float4 x = src[i];
    dst[i] = make_ushort4(f2b(x.x), f2b(x.y), f2b(x.z), f2b(x.w));
  } else {
    const int t = bid - 24576;
    const int z = t >> 10;
    const int rem = t & 1023;
    const int n0 = (rem & 31) * 32, k0 = (rem >> 5) * 32;
    const float* W = (z == 0) ? w0 : (z == 1) ? w1 : w2;
    unsigned short* WT = (z == 0) ? t0 : (z == 1) ? t1 : t2;
    const int tx = threadIdx.x & 31, ty = threadIdx.x >> 5;
#pragma unroll
    for (int i = 0; i < 32; i += 8)
      tl[ty + i][tx] = W[(size_t)(k0 + ty + i) * 1024 + (n0 + tx)];
    __syncthreads();
#pragma unroll
    for (int i = 0; i < 32; i += 8)
      WT[(size_t)(n0 + ty + i) * 1024 + (k0 + tx)] = f2b(tl[tx][ty + i]);
  }
}

// ---------------------------------------------------------------------------
// Row softmax: P[row,:] = softmax(BETA * S[row,:]) as bf16. One block/row.
// ---------------------------------------------------------------------------
__global__ __launch_bounds__(256) void softmax_rows(const float* __restrict__ S,
                                                    unsigned short* __restrict__ P) {
  const int cols = 2048;
  const size_t row = blockIdx.x;
  const float4* srow = (const float4*)(S + row * cols);
  const int tid = threadIdx.x;
  const int lane = tid & 63;
  const int wave = tid >> 6;

  float4 a = srow[tid];
  float4 b = srow[tid + 256];

  float mx = fmaxf(fmaxf(fmaxf(a.x, a.y), fmaxf(a.z, a.w)),
                   fmaxf(fmaxf(b.x, b.y), fmaxf(b.z, b.w)));
#pragma unroll
  for (int o = 1; o < 64; o <<= 1) mx = fmaxf(mx, __shfl_xor(mx, o));

  __shared__ float red[8];
  if (lane == 0) red[wave] = mx;
  __syncthreads();
  mx = fmaxf(fmaxf(red[0], red[1]), fmaxf(red[2], red[3]));

  const float c = 0.03125f * 1.4426950408889634f;  // BETA * log2(e)
  float4 pa, pb;
  pa.x = exp2f((a.x - mx) * c); pa.y = exp2f((a.y - mx) * c);
  pa.z = exp2f((a.z - mx) * c); pa.w = exp2f((a.w - mx) * c);
  pb.x = exp2f((b.x - mx) * c); pb.y = exp2f((b.y - mx) * c);
  pb.z = exp2f((b.z - mx) * c); pb.w = exp2f((b.w - mx) * c);

  float sum = pa.x + pa.y + pa.z + pa.w + pb.x + pb.y + pb.z + pb.w;
#pragma unroll
  for (int o = 1; o < 64; o <<= 1) sum += __shfl_xor(sum, o);
  if (lane == 0) red[4 + wave] = sum;
  __syncthreads();
  sum = red[4] + red[5] + red[6] + red[7];

  const float inv = 1.0f / sum;
  ushort4* prow = (ushort4*)(P + row * cols);
  prow[tid] = make_ushort4(f2b(pa.x * inv), f2b(pa.y * inv), f2b(pa.z * inv),
                           f2b(pa.w * inv));
  prow[tid + 256] = make_ushort4(f2b(pb.x * inv), f2b(pb.y * inv),
                                 f2b(pb.z * inv), f2b(pb.w * inv));
}

// ---------------------------------------------------------------------------
extern "C" void kernel_launch(void* const* d_in, const int* in_sizes, int n_in,
                              void* d_out, int out_size, void* d_ws, size_t ws_size,
                              hipStream_t stream) {
  const float* query = (const float*)d_in[0];
  const float* key_ = (const float*)d_in[1];
  const float* value = (const float*)d_in[2];
  const float* Wq = (const float*)d_in[3];
  const float* bq = (const float*)d_in[4];
  const float* Wk = (const float*)d_in[5];
  const float* bk = (const float*)d_in[6];
  const float* Wv = (const float*)d_in[7];
  const float* bv = (const float*)d_in[8];
  float* out = (float*)d_out;

  char* ws = (char*)d_ws;
  // Workspace layout (peak 166 MiB):
  //   [0,6)      WqT/WkT/WvT bf16 [1024,1024]
  //   [6,54)     Xq/Xk/Xv bf16 [8192,1024]   (reused for P after projections)
  //   [54,102)   q bf16 [8192,1024], k bf16 [8192,1024], vT bf16 [4][1024,2048]
  //   [102,166)  scores fp32 [4,2048,2048]
  unsigned short* WqT = (unsigned short*)ws;
  unsigned short* WkT = WqT + (size_t)1024 * 1024;
  unsigned short* WvT = WkT + (size_t)1024 * 1024;
  unsigned short* Xq = (unsigned short*)(ws + 6 * MIB);
  unsigned short* Xk = Xq + (size_t)8192 * 1024;
  unsigned short* Xv = Xk + (size_t)8192 * 1024;
  unsigned short* qb = (unsigned short*)(ws + 54 * MIB);
  unsigned short* kb = (unsigned short*)(ws + 70 * MIB);
  unsigned short* vT = (unsigned short*)(ws + 86 * MIB);
  float* sc = (float*)(ws + 102 * MIB);
  unsigned short* P = (unsigned short*)(ws + 6 * MIB);  // reuse X region

  // prep: cast (24576 blocks) + weight transpose (3072 blocks), one dispatch.
  prep<<<dim3(27648), 256, 0, stream>>>(
      (const float4*)query, (const float4*)key_, (const float4*)value,
      (ushort4*)Xq, (ushort4*)Xk, (ushort4*)Xv, Wq, Wk, Wv, WqT, WkT, WvT);

  ProjArgs pa;
  pa.A[0] = Xq;  pa.A[1] = Xk;  pa.A[2] = Xv;
  pa.Bt[0] = WqT; pa.Bt[1] = WkT; pa.Bt[2] = WvT;
  pa.C[0] = qb;  pa.C[1] = kb;  pa.C[2] = vT;
  pa.bias[0] = bq; pa.bias[1] = bk; pa.bias[2] = bv;

  // q,k projections: m-fastest grid (64,8,2) = 1024 blocks.
  proj_qk<<<dim3(64, 8, 2), 256, 0, stream>>>(pa);
  // v projection: m-fastest grid (64,8,1) = 512 blocks.
  proj_v<<<dim3(64, 8, 1), 256, 0, stream>>>(pa);

  // scores[b] = q[b] @ k[b]^T : M=N=2048, K=1024, fp32. m-fastest (16,16,4).
  gemm_f32<<<dim3(16, 16, 4), 256, 0, stream>>>(
      qb, kb, sc, 1024, 2048, 2048LL * 1024, 2048LL * 1024, 2048LL * 2048);

  // P = softmax(BETA * scores), bf16
  softmax_rows<<<8192, 256, 0, stream>>>(sc, P);

  // out[b] = P[b] @ v[b] : M=2048, N=1024, K=2048. m-fastest (16,8,4).
  gemm_f32<<<dim3(16, 8, 4), 256, 0, stream>>>(
      P, vT, out, 2048, 1024, 2048LL * 2048, 1024LL * 2048, 2048LL * 1024);
}

// Round 9
// 305.821 us; speedup vs baseline: 1.1885x; 1.0454x over previous
//
#include <hip/hip_runtime.h>

// ---------------------------------------------------------------------------
// Attention: out = softmax(BETA * (X_q Wq + bq)(X_k Wk + bk)^T) (X_v Wv + bv)
// B=4, S=2048, D=1024, KEY_DIM=VALUE_DIM=1024, BETA=1/32.
// R15 = R14 (319.7us) + 256x256/8-wave core for proj_qk and scores.
//  R14 analysis: with FETCH near-ideal, GEMMs are LDS-READ-BW bound:
//  64x64 wave tile = 1/16 B/FLOP -> ~840 TF ceiling (matches 660 measured).
//  Wave tile 128x64 (8 waves, 256^2 block) halves LDS bytes/FLOP.
//  Schedule stays the PROVEN R11 2-phase form (stage(t+1); reads+MFMA in 2
//  ks-phases; ONE syncthreads per K-tile) - NOT R8's 8-barrier lockstep.
//  Same XOR-swizzled 64-elem rows (read pattern per wave unchanged -> 0
//  conflicts). ks=1 frag offset = ks=0 XOR 64 (chunk bit2 flip).
//  Grids m-fastest (XCD panel locality, R14's win): proj_qk (32,4,2)=256
//  blocks, scores (8,8,4)=256 blocks = 1/CU. proj_v + PV keep R14 path.
// ---------------------------------------------------------------------------

typedef __bf16 bf16x8 __attribute__((ext_vector_type(8)));
typedef float f32x4 __attribute__((ext_vector_type(4)));

#define MIB ((size_t)1 << 20)

__device__ __forceinline__ unsigned short f2b(float f) {
  unsigned int u = __float_as_uint(f);
  return (unsigned short)((u + 0x7FFFu + ((u >> 16) & 1u)) >> 16);
}

__device__ __forceinline__ void async16(const void* g, void* l) {
  __builtin_amdgcn_global_load_lds(
      (const __attribute__((address_space(1))) unsigned int*)g,
      (__attribute__((address_space(3))) unsigned int*)l, 16, 0, 0);
}

__device__ __forceinline__ unsigned ldsoff(const void* p) {
  return (unsigned)(size_t)(const __attribute__((address_space(3))) char*)p;
}

// Raw b128 LDS read, invisible to the compiler's waitcnt insertion.
__device__ __forceinline__ bf16x8 ds_read16(unsigned off) {
  bf16x8 r;
  asm volatile("ds_read_b128 %0, %1" : "=v"(r) : "v"(off));
  return r;
}

// ===========================================================================
// 256x256 / 8-wave / wave-tile 128x64 core (2-phase, 1 barrier per K-tile).
// LDS buffer (64KB x2): [A 256x64 bf16 | B 256x64 bf16], 64-elem rows,
// chunk slot (r,cc) holds global chunk (r, cc^(r&7)).
// acc is SWAPPED fragment: row m = fr (+16*mi), cols n = q4..q4+3 (+16*ni).
// ===========================================================================
__device__ __forceinline__ void stage256(
    const unsigned short* __restrict__ Ab, const unsigned short* __restrict__ Bb,
    unsigned short* dst, int K, int kb, int tid) {
#pragma unroll
  for (int i = 0; i < 4; ++i) {
    const int e = i * 512 + tid;  // 2048 chunks of 8 bf16
    const int r = e >> 3;
    const int cg = (e & 7) ^ (r & 7);
    async16(Ab + (size_t)r * K + kb + cg * 8, dst + e * 8);
  }
#pragma unroll
  for (int i = 0; i < 4; ++i) {
    const int e = i * 512 + tid;
    const int r = e >> 3;
    const int cg = (e & 7) ^ (r & 7);
    async16(Bb + (size_t)r * K + kb + cg * 8, dst + 16384 + e * 8);
  }
}

__device__ __forceinline__ void gemm256(
    const unsigned short* __restrict__ A, const unsigned short* __restrict__ Bt,
    unsigned short* lds, int K, int m0, int n0, f32x4 (&acc)[8][4]) {
  const int tid = threadIdx.x;
  const int lane = tid & 63;
  const int wave = tid >> 6;
  const int wm = (wave >> 2) * 128;  // waves 0-3: m 0-127; 4-7: m 128-255
  const int wn = (wave & 3) * 64;    // n quadrant
  const int fr = lane & 15;
  const int q = lane >> 4;
  const int NT = K >> 6;

  const unsigned short* Ab = A + (size_t)m0 * K;
  const unsigned short* Bb = Bt + (size_t)n0 * K;
  const unsigned LB = ldsoff(lds);

  // ks=0 fragment byte offsets within a buffer; ks=1 = XOR 64 (chunk bit2).
  unsigned oa[8], ob[4];
#pragma unroll
  for (int mi = 0; mi < 8; ++mi) {
    const int R = wm + mi * 16 + fr;
    oa[mi] = (unsigned)((R * 64 + ((q ^ (R & 7)) << 3)) * 2);
  }
#pragma unroll
  for (int ni = 0; ni < 4; ++ni) {
    const int R = wn + ni * 16 + fr;
    ob[ni] = (unsigned)(32768 + (R * 64 + ((q ^ (R & 7)) << 3)) * 2);
  }

  stage256(Ab, Bb, lds, K, 0, tid);
  __syncthreads();  // vmcnt(0)+barrier: tile 0 resident

  for (int t = 0; t < NT; ++t) {
    const unsigned boff = LB + (unsigned)(t & 1) * 65536;
    if (t + 1 < NT)
      stage256(Ab, Bb, lds + ((t + 1) & 1) * 32768, K, (t + 1) << 6, tid);

#pragma unroll
    for (int ks = 0; ks < 2; ++ks) {
      const unsigned kx = ks ? 64u : 0u;
      bf16x8 av[8], bv[4];
#pragma unroll
      for (int mi = 0; mi < 8; ++mi) av[mi] = ds_read16((boff + oa[mi]) ^ kx);
#pragma unroll
      for (int ni = 0; ni < 4; ++ni) bv[ni] = ds_read16((boff + ob[ni]) ^ kx);

      asm volatile("s_waitcnt lgkmcnt(0)");
      __builtin_amdgcn_sched_barrier(0);

#pragma unroll
      for (int mi = 0; mi < 8; ++mi)
#pragma unroll
        for (int ni = 0; ni < 4; ++ni)
          acc[mi][ni] = __builtin_amdgcn_mfma_f32_16x16x32_bf16(
              bv[ni], av[mi], acc[mi][ni], 0, 0, 0);  // swapped
    }
    __syncthreads();  // tile t+1 resident; frees buffer t
  }
}

// ---------------------------------------------------------------------------
// q/k projection, 256^2 tiles, grid (32, 4, 2) m-fastest: z = {q,k}.
// ---------------------------------------------------------------------------
struct ProjArgs {
  const unsigned short* A[3];
  const unsigned short* Bt[3];
  unsigned short* C[3];
  const float* bias[3];
};

__global__ __launch_bounds__(512, 2) void proj_qk256(ProjArgs p) {
  __shared__ __align__(16) unsigned short lds[65536];  // 128 KB
  const int z = blockIdx.z;
  const int m0 = blockIdx.x * 256;  // m fastest (XCD panel locality)
  const int n0 = blockIdx.y * 256;

  f32x4 acc[8][4] = {};
  gemm256(p.A[z], p.Bt[z], lds, 1024, m0, n0, acc);

  const int lane = threadIdx.x & 63;
  const int wave = threadIdx.x >> 6;
  const int wm = (wave >> 2) * 128;
  const int wn = (wave & 3) * 64;
  const int fr = lane & 15;
  const int q4 = (lane >> 4) * 4;
  const float* bias = p.bias[z];
  unsigned short* C = p.C[z];

#pragma unroll
  for (int mi = 0; mi < 8; ++mi) {
    const int m = m0 + wm + mi * 16 + fr;
#pragma unroll
    for (int ni = 0; ni < 4; ++ni) {
      const int nb = n0 + wn + ni * 16 + q4;
      const float4 bb = *(const float4*)&bias[nb];
      ushort4 o = make_ushort4(
          f2b(acc[mi][ni][0] + bb.x), f2b(acc[mi][ni][1] + bb.y),
          f2b(acc[mi][ni][2] + bb.z), f2b(acc[mi][ni][3] + bb.w));
      *(ushort4*)&C[(size_t)m * 1024 + nb] = o;
    }
  }
}

// ---------------------------------------------------------------------------
// scores[b] = q[b] @ k[b]^T, 256^2 tiles, grid (8, 8, 4) m-fastest, fp32 out.
// ---------------------------------------------------------------------------
__global__ __launch_bounds__(512, 2) void score256(
    const unsigned short* __restrict__ qb, const unsigned short* __restrict__ kb,
    float* __restrict__ sc) {
  __shared__ __align__(16) unsigned short lds[65536];
  const int bz = blockIdx.z;
  const int m0 = blockIdx.x * 256;
  const int n0 = blockIdx.y * 256;

  f32x4 acc[8][4] = {};
  gemm256(qb + (size_t)bz * (2048 * 1024), kb + (size_t)bz * (2048 * 1024),
          lds, 1024, m0, n0, acc);

  float* C = sc + (size_t)bz * (2048 * 2048);
  const int lane = threadIdx.x & 63;
  const int wave = threadIdx.x >> 6;
  const int wm = (wave >> 2) * 128;
  const int wn = (wave & 3) * 64;
  const int fr = lane & 15;
  const int q4 = (lane >> 4) * 4;
#pragma unroll
  for (int mi = 0; mi < 8; ++mi) {
    const int m = m0 + wm + mi * 16 + fr;
#pragma unroll
    for (int ni = 0; ni < 4; ++ni) {
      const int nb = n0 + wn + ni * 16 + q4;
      *(f32x4*)&C[(size_t)m * 2048 + nb] = acc[mi][ni];
    }
  }
}

// ===========================================================================
// R14 128^2 core (kept for proj_v and PV).
// ===========================================================================
template <int TN>
__device__ __forceinline__ void stage_tile(
    const unsigned short* __restrict__ A, const unsigned short* __restrict__ Bt,
    unsigned short* dst, int K, int kb, int tid) {
#pragma unroll
  for (int i = 0; i < 4; ++i) {
    const int e = i * 256 + tid;
    const int r = e >> 3;
    const int cg = (e & 7) ^ (r & 7);
    async16(A + (size_t)r * K + kb + cg * 8, dst + e * 8);
  }
#pragma unroll
  for (int i = 0; i < TN / 32; ++i) {
    const int e = i * 256 + tid;
    const int r = e >> 3;
    const int cg = (e & 7) ^ (r & 7);
    async16(Bt + (size_t)r * K + kb + cg * 8, dst + 128 * 64 + e * 8);
  }
}

template <int TN, bool SWAP>
__device__ __forceinline__ void gemm_loop(
    const unsigned short* __restrict__ A, const unsigned short* __restrict__ Bt,
    unsigned short* lds, int K, int m0, int n0, f32x4 (&acc)[4][TN / 32]) {
  constexpr int NI = TN / 32;
  constexpr unsigned BUFB = (128 + TN) * 64 * 2;  // bytes per buffer
  const int tid = threadIdx.x;
  const int lane = tid & 63;
  const int wave = tid >> 6;
  const int wm = (wave >> 1) * 64;
  const int wn = (wave & 1) * (TN / 2);
  const int fr = lane & 15;
  const int q = lane >> 4;
  const int NT = K >> 6;

  const unsigned short* Ab = A + (size_t)m0 * K;
  const unsigned short* Bb = Bt + (size_t)n0 * K;
  const unsigned LB = ldsoff(lds);

  unsigned oa[4][2], ob[NI][2];
#pragma unroll
  for (int mi = 0; mi < 4; ++mi) {
    const int R = wm + mi * 16 + fr;
#pragma unroll
    for (int ks = 0; ks < 2; ++ks) {
      const int kc = ks * 4 + q;
      oa[mi][ks] = (unsigned)((R * 64 + ((kc ^ (R & 7)) << 3)) * 2);
    }
  }
#pragma unroll
  for (int ni = 0; ni < NI; ++ni) {
    const int R = wn + ni * 16 + fr;
#pragma unroll
    for (int ks = 0; ks < 2; ++ks) {
      const int kc = ks * 4 + q;
      ob[ni][ks] =
          (unsigned)(128 * 64 * 2 + (R * 64 + ((kc ^ (R & 7)) << 3)) * 2);
    }
  }

  stage_tile<TN>(Ab, Bb, lds, K, 0, tid);
  __syncthreads();

  for (int t = 0; t < NT; ++t) {
    const unsigned boff = LB + (unsigned)(t & 1) * BUFB;
    if (t + 1 < NT)
      stage_tile<TN>(Ab, Bb, lds + ((t + 1) & 1) * (BUFB / 2), K,
                     (t + 1) << 6, tid);

    bf16x8 av[2][4], bv[2][NI];
#pragma unroll
    for (int ks = 0; ks < 2; ++ks)
#pragma unroll
      for (int mi = 0; mi < 4; ++mi) av[ks][mi] = ds_read16(boff + oa[mi][ks]);
#pragma unroll
    for (int ks = 0; ks < 2; ++ks)
#pragma unroll
      for (int ni = 0; ni < NI; ++ni) bv[ks][ni] = ds_read16(boff + ob[ni][ks]);

    asm volatile("s_waitcnt lgkmcnt(0)");
    __builtin_amdgcn_sched_barrier(0);

#pragma unroll
    for (int ks = 0; ks < 2; ++ks)
#pragma unroll
      for (int mi = 0; mi < 4; ++mi)
#pragma unroll
        for (int ni = 0; ni < NI; ++ni)
          acc[mi][ni] = SWAP ? __builtin_amdgcn_mfma_f32_16x16x32_bf16(
                                   bv[ks][ni], av[ks][mi], acc[mi][ni], 0, 0, 0)
                             : __builtin_amdgcn_mfma_f32_16x16x32_bf16(
                                   av[ks][mi], bv[ks][ni], acc[mi][ni], 0, 0, 0);

    __syncthreads();
  }
}

// ---------------------------------------------------------------------------
// v projection GEMM (unswapped), grid (64, 8, 1): writes vT[b][n][s].
// ---------------------------------------------------------------------------
__global__ __launch_bounds__(256) void proj_v(ProjArgs p) {
  __shared__ __align__(16) unsigned short lds[2 * 256 * 64];
  const int m0 = blockIdx.x * 128;  // m fastest
  const int n0 = blockIdx.y * 128;

  f32x4 acc[4][4] = {};
  gemm_loop<128, false>(p.A[2], p.Bt[2], lds, 1024, m0, n0, acc);

  const int lane = threadIdx.x & 63;
  const int wave = threadIdx.x >> 6;
  const int wm = (wave >> 1) * 64;
  const int wn = (wave & 1) * 64;
  const int fr = lane & 15;
  const int q4 = (lane >> 4) * 4;
  const float* bias = p.bias[2];

  // vT: per-batch [1024, 2048]; col n = fr (+16*ni), rows m = q4+r (+16*mi).
  unsigned short* C = p.C[2] + (size_t)(m0 >> 11) * (2048 * 1024);
#pragma unroll
  for (int mi = 0; mi < 4; ++mi) {
#pragma unroll
    for (int ni = 0; ni < 4; ++ni) {
      const int col = n0 + wn + ni * 16 + fr;
      const float bb = bias[col];
      const int rowb = (m0 + wm + mi * 16 + q4) & 2047;
      ushort4 o =
          make_ushort4(f2b(acc[mi][ni][0] + bb), f2b(acc[mi][ni][1] + bb),
                       f2b(acc[mi][ni][2] + bb), f2b(acc[mi][ni][3] + bb));
      *(ushort4*)&C[(size_t)col * 2048 + rowb] = o;
    }
  }
}

// ---------------------------------------------------------------------------
// Batched GEMM (PV), fp32 out (SWAP layout -> float4 stores), m-fastest.
// ---------------------------------------------------------------------------
__global__ __launch_bounds__(256) void gemm_f32(
    const unsigned short* __restrict__ A, const unsigned short* __restrict__ Bt,
    float* __restrict__ C, int K, int ldc, long long sA, long long sB,
    long long sC) {
  __shared__ __align__(16) unsigned short lds[2 * 256 * 64];
  const int bz = blockIdx.z;
  A += (long long)bz * sA;
  Bt += (long long)bz * sB;
  C += (long long)bz * sC;
  const int m0 = blockIdx.x * 128;  // m fastest
  const int n0 = blockIdx.y * 128;

  f32x4 acc[4][4] = {};
  gemm_loop<128, true>(A, Bt, lds, K, m0, n0, acc);

  const int lane = threadIdx.x & 63;
  const int wave = threadIdx.x >> 6;
  const int wm = (wave >> 1) * 64;
  const int wn = (wave & 1) * 64;
  const int fr = lane & 15;
  const int q4 = (lane >> 4) * 4;
#pragma unroll
  for (int mi = 0; mi < 4; ++mi) {
    const int m = m0 + wm + mi * 16 + fr;
#pragma unroll
    for (int ni = 0; ni < 4; ++ni) {
      const int nb = n0 + wn + ni * 16 + q4;
      *(f32x4*)&C[(size_t)m * ldc + nb] = acc[mi][ni];
    }
  }
}

// ---------------------------------------------------------------------------
// prep: cast3 (fp32->bf16, 3 tensors) + transpose3 (W->WT bf16) in ONE
// dispatch. Blocks [0,24576): cast; [24576,27648): transpose. 256 threads.
// ---------------------------------------------------------------------------
__global__ __launch_bounds__(256) void prep(
    const float4* __restrict__ xq, const float4* __restrict__ xk,
    const float4* __restrict__ xv, ushort4* __restrict__ oq,
    ushort4* __restrict__ ok, ushort4* __restrict__ ov,
    const float* __restrict__ w0, const float* __restrict__ w1,
    const float* __restrict__ w2, unsigned short* __restrict__ t0,
    unsigned short* __restrict__ t1, unsigned short* __restrict__ t2) {
  __shared__ float tl[32][33];
  const int bid = blockIdx.x;
  if (bid < 24576) {
    const int ten = bid >> 13;  // 8192 blocks per tensor
    const int i = (bid & 8191) * 256 + threadIdx.x;
    const float4* src = (ten == 0) ? xq : (ten == 1) ? xk : xv;
    ushort4* dst = (ten == 0) ? oq : (ten == 1) ? ok : ov;
    float4 x = src[i];
    dst[i] = make_ushort4(f2b(x.x), f2b(x.y), f2b(x.z), f2b(x.w));
  } else {
    const int t = bid - 24576;
    const int z = t >> 10;
    const int rem = t & 1023;
    const int n0 = (rem & 31) * 32, k0 = (rem >> 5) * 32;
    const float* W = (z == 0) ? w0 : (z == 1) ? w1 : w2;
    unsigned short* WT = (z == 0) ? t0 : (z == 1) ? t1 : t2;
    const int tx = threadIdx.x & 31, ty = threadIdx.x >> 5;
#pragma unroll
    for (int i = 0; i < 32; i += 8)
      tl[ty + i][tx] = W[(size_t)(k0 + ty + i) * 1024 + (n0 + tx)];
    __syncthreads();
#pragma unroll
    for (int i = 0; i < 32; i += 8)
      WT[(size_t)(n0 + ty + i) * 1024 + (k0 + tx)] = f2b(tl[tx][ty + i]);
  }
}

// ---------------------------------------------------------------------------
// Row softmax: P[row,:] = softmax(BETA * S[row,:]) as bf16. One block/row.
// ---------------------------------------------------------------------------
__global__ __launch_bounds__(256) void softmax_rows(const float* __restrict__ S,
                                                    unsigned short* __restrict__ P) {
  const int cols = 2048;
  const size_t row = blockIdx.x;
  const float4* srow = (const float4*)(S + row * cols);
  const int tid = threadIdx.x;
  const int lane = tid & 63;
  const int wave = tid >> 6;

  float4 a = srow[tid];
  float4 b = srow[tid + 256];

  float mx = fmaxf(fmaxf(fmaxf(a.x, a.y), fmaxf(a.z, a.w)),
                   fmaxf(fmaxf(b.x, b.y), fmaxf(b.z, b.w)));
#pragma unroll
  for (int o = 1; o < 64; o <<= 1) mx = fmaxf(mx, __shfl_xor(mx, o));

  __shared__ float red[8];
  if (lane == 0) red[wave] = mx;
  __syncthreads();
  mx = fmaxf(fmaxf(red[0], red[1]), fmaxf(red[2], red[3]));

  const float c = 0.03125f * 1.4426950408889634f;  // BETA * log2(e)
  float4 pa, pb;
  pa.x = exp2f((a.x - mx) * c); pa.y = exp2f((a.y - mx) * c);
  pa.z = exp2f((a.z - mx) * c); pa.w = exp2f((a.w - mx) * c);
  pb.x = exp2f((b.x - mx) * c); pb.y = exp2f((b.y - mx) * c);
  pb.z = exp2f((b.z - mx) * c); pb.w = exp2f((b.w - mx) * c);

  float sum = pa.x + pa.y + pa.z + pa.w + pb.x + pb.y + pb.z + pb.w;
#pragma unroll
  for (int o = 1; o < 64; o <<= 1) sum += __shfl_xor(sum, o);
  if (lane == 0) red[4 + wave] = sum;
  __syncthreads();
  sum = red[4] + red[5] + red[6] + red[7];

  const float inv = 1.0f / sum;
  ushort4* prow = (ushort4*)(P + row * cols);
  prow[tid] = make_ushort4(f2b(pa.x * inv), f2b(pa.y * inv), f2b(pa.z * inv),
                           f2b(pa.w * inv));
  prow[tid + 256] = make_ushort4(f2b(pb.x * inv), f2b(pb.y * inv),
                                 f2b(pb.z * inv), f2b(pb.w * inv));
}

// ---------------------------------------------------------------------------
extern "C" void kernel_launch(void* const* d_in, const int* in_sizes, int n_in,
                              void* d_out, int out_size, void* d_ws, size_t ws_size,
                              hipStream_t stream) {
  const float* query = (const float*)d_in[0];
  const float* key_ = (const float*)d_in[1];
  const float* value = (const float*)d_in[2];
  const float* Wq = (const float*)d_in[3];
  const float* bq = (const float*)d_in[4];
  const float* Wk = (const float*)d_in[5];
  const float* bk = (const float*)d_in[6];
  const float* Wv = (const float*)d_in[7];
  const float* bv = (const float*)d_in[8];
  float* out = (float*)d_out;

  char* ws = (char*)d_ws;
  // Workspace layout (peak 166 MiB):
  //   [0,6)      WqT/WkT/WvT bf16 [1024,1024]
  //   [6,54)     Xq/Xk/Xv bf16 [8192,1024]   (reused for P after projections)
  //   [54,102)   q bf16 [8192,1024], k bf16 [8192,1024], vT bf16 [4][1024,2048]
  //   [102,166)  scores fp32 [4,2048,2048]
  unsigned short* WqT = (unsigned short*)ws;
  unsigned short* WkT = WqT + (size_t)1024 * 1024;
  unsigned short* WvT = WkT + (size_t)1024 * 1024;
  unsigned short* Xq = (unsigned short*)(ws + 6 * MIB);
  unsigned short* Xk = Xq + (size_t)8192 * 1024;
  unsigned short* Xv = Xk + (size_t)8192 * 1024;
  unsigned short* qb = (unsigned short*)(ws + 54 * MIB);
  unsigned short* kb = (unsigned short*)(ws + 70 * MIB);
  unsigned short* vT = (unsigned short*)(ws + 86 * MIB);
  float* sc = (float*)(ws + 102 * MIB);
  unsigned short* P = (unsigned short*)(ws + 6 * MIB);  // reuse X region

  // prep: cast (24576 blocks) + weight transpose (3072 blocks), one dispatch.
  prep<<<dim3(27648), 256, 0, stream>>>(
      (const float4*)query, (const float4*)key_, (const float4*)value,
      (ushort4*)Xq, (ushort4*)Xk, (ushort4*)Xv, Wq, Wk, Wv, WqT, WkT, WvT);

  ProjArgs pa;
  pa.A[0] = Xq;  pa.A[1] = Xk;  pa.A[2] = Xv;
  pa.Bt[0] = WqT; pa.Bt[1] = WkT; pa.Bt[2] = WvT;
  pa.C[0] = qb;  pa.C[1] = kb;  pa.C[2] = vT;
  pa.bias[0] = bq; pa.bias[1] = bk; pa.bias[2] = bv;

  // q,k projections: 256^2 tiles, m-fastest grid (32,4,2) = 256 blocks.
  proj_qk256<<<dim3(32, 4, 2), 512, 0, stream>>>(pa);
  // v projection: 128^2 path, m-fastest grid (64,8,1) = 512 blocks.
  proj_v<<<dim3(64, 8, 1), 256, 0, stream>>>(pa);

  // scores: 256^2 tiles, m-fastest grid (8,8,4) = 256 blocks (1/CU).
  score256<<<dim3(8, 8, 4), 512, 0, stream>>>(qb, kb, sc);

  // P = softmax(BETA * scores), bf16
  softmax_rows<<<8192, 256, 0, stream>>>(sc, P);

  // out[b] = P[b] @ v[b] : M=2048, N=1024, K=2048. m-fastest (16,8,4).
  gemm_f32<<<dim3(16, 8, 4), 256, 0, stream>>>(
      P, vT, out, 2048, 1024, 2048LL * 2048, 1024LL * 2048, 2048LL * 1024);
}